// Round 1
// baseline (637.883 us; speedup 1.0000x reference)
//
#include <hip/hip_runtime.h>
#include <hip/hip_bf16.h>

// GlobalAttention (general): B=32, T=512, S=1024, D=1024, f32 in/out.
//   h = in @ W_in^T            (split3 bf16 MFMA -> h_hi/h_lo planes)
//   align = h @ ctx^T          (split3 -> f32 logits in d_out align region)
//   P = softmax(align)         (f32 in-place, + p_hi/p_lo planes)
//   c = P @ ctx                (split3, B = transposed ctx planes -> c_hi/c_lo)
//   attn = tanh(concat[c,in] @ W_out^T)   (split-A x plain-B, 2-term)
//
// Workspace map (bytes), with dead-region reuse; total 276,824,064 (~264MB):
//   [0,64M)    ctx_hi        -> after GEMM2: c_hi [0,32M), c_lo [32M,64M)
//   [64M,128M) ctx_lo        -> after GEMM2: p_hi [64M,96M), p_lo [96M,128M)
//   [128M,192M) in_hi, in_lo (live through GEMM4)
//   [192M,256M) h_hi, h_lo   -> after GEMM2: ctxT_lo (64M)
//   [256M,..)  win_hi(2M) win_lo(2M) wout_bf(4M)
// ctxT_hi lives in d_out's attn_h region (64MB) until GEMM4 overwrites it.

typedef short bf16x8 __attribute__((ext_vector_type(8)));
typedef float f32x4 __attribute__((ext_vector_type(4)));
typedef unsigned short us;

#define NB 32
#define NT 512
#define NS 1024
#define ND 1024

__device__ inline us f2bf(float x) {
  unsigned u = __float_as_uint(x);
  u += 0x7FFFu + ((u >> 16) & 1u);
  return (us)(u >> 16);
}
__device__ inline float bf2f(us h) { return __uint_as_float(((unsigned)h) << 16); }

__device__ inline void store_split(us* __restrict__ hi, us* __restrict__ lo, size_t idx, float v) {
  us h = f2bf(v);
  hi[idx] = h;
  lo[idx] = f2bf(v - bf2f(h));
}

// ---------------- elementwise split / convert ----------------
__global__ void ga_split(const float* __restrict__ src, us* __restrict__ hi,
                         us* __restrict__ lo, long n) {
  long i0 = ((long)blockIdx.x * blockDim.x + threadIdx.x) * 4;
  long stride = (long)gridDim.x * blockDim.x * 4;
  for (long i = i0; i < n; i += stride) {
    float4 v = *reinterpret_cast<const float4*>(src + i);
    ushort4 h, l;
    h.x = f2bf(v.x); l.x = f2bf(v.x - bf2f(h.x));
    h.y = f2bf(v.y); l.y = f2bf(v.y - bf2f(h.y));
    h.z = f2bf(v.z); l.z = f2bf(v.z - bf2f(h.z));
    h.w = f2bf(v.w); l.w = f2bf(v.w - bf2f(h.w));
    *reinterpret_cast<ushort4*>(hi + i) = h;
    *reinterpret_cast<ushort4*>(lo + i) = l;
  }
}

__global__ void ga_cvt(const float* __restrict__ src, us* __restrict__ dst, long n) {
  long i0 = ((long)blockIdx.x * blockDim.x + threadIdx.x) * 4;
  long stride = (long)gridDim.x * blockDim.x * 4;
  for (long i = i0; i < n; i += stride) {
    float4 v = *reinterpret_cast<const float4*>(src + i);
    ushort4 h;
    h.x = f2bf(v.x); h.y = f2bf(v.y); h.z = f2bf(v.z); h.w = f2bf(v.w);
    *reinterpret_cast<ushort4*>(dst + i) = h;
  }
}

// ---------------- ctx transpose+split: [B][S][D] f32 -> [B][D][S] bf16 hi/lo ----------------
__global__ void ga_transpose_split(const float* __restrict__ ctx, us* __restrict__ tHi,
                                   us* __restrict__ tLo) {
  __shared__ float tile[64][65];
  int s0 = blockIdx.x << 6, d0 = blockIdx.y << 6, b = blockIdx.z;
  const float* src = ctx + (size_t)b * NS * ND;
  int tid = threadIdx.x;
#pragma unroll
  for (int i = 0; i < 16; ++i) {
    int lin = (i << 8) + tid;
    int r = lin >> 6, c = lin & 63;
    tile[r][c] = src[(size_t)(s0 + r) * ND + d0 + c];
  }
  __syncthreads();
  us* oH = tHi + (size_t)b * ND * NS;
  us* oL = tLo + (size_t)b * ND * NS;
#pragma unroll
  for (int i = 0; i < 16; ++i) {
    int lin = (i << 8) + tid;
    int dr = lin >> 6, sc = lin & 63;
    float v = tile[sc][dr];
    size_t o = (size_t)(d0 + dr) * NS + s0 + sc;
    us h = f2bf(v);
    oH[o] = h;
    oL[o] = f2bf(v - bf2f(h));
  }
}

// ---------------- row softmax over align [rows=(t*32+b)][1024], in-place f32 + split planes ----------------
__global__ __launch_bounds__(256) void ga_softmax(float* __restrict__ al,
                                                  us* __restrict__ pHi, us* __restrict__ pLo) {
  int row = blockIdx.x;  // t*32 + b
  int tid = threadIdx.x;
  float* p = al + (size_t)row * NS;
  float4 v = *reinterpret_cast<const float4*>(p + (tid << 2));
  float m = fmaxf(fmaxf(v.x, v.y), fmaxf(v.z, v.w));
#pragma unroll
  for (int off = 32; off; off >>= 1) m = fmaxf(m, __shfl_xor(m, off));
  __shared__ float rmax[4], rsum[4];
  int wv = tid >> 6, ln = tid & 63;
  if (ln == 0) rmax[wv] = m;
  __syncthreads();
  m = fmaxf(fmaxf(rmax[0], rmax[1]), fmaxf(rmax[2], rmax[3]));
  float4 e;
  e.x = __expf(v.x - m); e.y = __expf(v.y - m);
  e.z = __expf(v.z - m); e.w = __expf(v.w - m);
  float s = e.x + e.y + e.z + e.w;
#pragma unroll
  for (int off = 32; off; off >>= 1) s += __shfl_xor(s, off);
  if (ln == 0) rsum[wv] = s;
  __syncthreads();
  s = rsum[0] + rsum[1] + rsum[2] + rsum[3];
  float inv = 1.0f / s;
  e.x *= inv; e.y *= inv; e.z *= inv; e.w *= inv;
  *reinterpret_cast<float4*>(p + (tid << 2)) = e;
  int t = row >> 5, b = row & 31;
  size_t o = ((size_t)b * NT + t) * NS + (tid << 2);
  ushort4 h, l;
  h.x = f2bf(e.x); l.x = f2bf(e.x - bf2f(h.x));
  h.y = f2bf(e.y); l.y = f2bf(e.y - bf2f(h.y));
  h.z = f2bf(e.z); l.z = f2bf(e.z - bf2f(h.z));
  h.w = f2bf(e.w); l.w = f2bf(e.w - bf2f(h.w));
  *reinterpret_cast<ushort4*>(pHi + o) = h;
  *reinterpret_cast<ushort4*>(pLo + o) = l;
}

// ---------------- GEMM: C[M,N] = A[M,K] * B[N,K]^T, 128x128 tile, BK=64, split-bf16 ----------------
__device__ inline void gload16(const us* g, us* l) {
  __builtin_amdgcn_global_load_lds((const __attribute__((address_space(1))) unsigned int*)g,
                                   (__attribute__((address_space(3))) unsigned int*)l, 16, 0, 0);
}

// Stage 128x64 bf16 tile; LDS holds XOR-swizzled layout via pre-swizzled global source.
__device__ inline void stage_plane(const us* __restrict__ src, int ld, us* __restrict__ tile, int tid) {
  int r = tid >> 3;                              // 0..31
  int cs = (((tid & 7) ^ (r & 7)) << 3);         // swizzled source column (elements)
  const us* g = src + (size_t)r * ld + cs;
  us* l = tile + (tid << 3);                     // 16B per thread, linear
#pragma unroll
  for (int s = 0; s < 4; ++s) gload16(g + (size_t)(s * 32) * ld, l + s * 2048);
}

__device__ inline bf16x8 frag_ld(const us* tile, int row, int colb) {
  int off = (row << 7) + (colb ^ ((row & 7) << 4));
  return *reinterpret_cast<const bf16x8*>(reinterpret_cast<const char*>(tile) + off);
}

__device__ inline f32x4 mfma16(bf16x8 a, bf16x8 b, f32x4 c) {
  return __builtin_amdgcn_mfma_f32_16x16x32_bf16(a, b, c, 0, 0, 0);
}

// MODE 0: GEMM1 in*W_in^T -> h hi/lo planes.        grid(128,8,1)
// MODE 1: GEMM2 h*ctx^T   -> f32 align (t*32+b,s).  grid(4,8,32)
// MODE 2: GEMM3 P*ctxT^T  -> c hi/lo planes.        grid(4,8,32)
// MODE 3: GEMM4 concat[c,in]*W_out^T -> tanh f32.   grid(128,8,1), 2-term
template <int MODE>
__global__ __launch_bounds__(256, 2) void ga_gemm(
    const us* __restrict__ Ahi, const us* __restrict__ Alo,
    const us* __restrict__ A2hi, const us* __restrict__ A2lo,
    const us* __restrict__ Bhi, const us* __restrict__ Blo,
    void* __restrict__ out0, void* __restrict__ out1,
    int K, int lda, int ldb, long astride, long bstride) {
  constexpr int NTILES = (MODE == 3) ? 3 : 4;
  __shared__ __align__(16) us lds[NTILES * 8192];
  us* tAh = lds;
  us* tBh = lds + 8192;
  us* tAl = lds + 16384;
  us* tBl = (MODE == 3) ? nullptr : lds + 24576;

  int tid = threadIdx.x;
  int bx = blockIdx.x, by = blockIdx.y, bz = blockIdx.z;
  int rowA = bx * 128, colB = by * 128;

  const us* pAh = Ahi + (size_t)bz * astride + (size_t)rowA * lda;
  const us* pAl = Alo + (size_t)bz * astride + (size_t)rowA * lda;
  const us* pA2h = (MODE == 3) ? A2hi + (size_t)rowA * lda : nullptr;
  const us* pA2l = (MODE == 3) ? A2lo + (size_t)rowA * lda : nullptr;
  const us* pBh = Bhi + (size_t)bz * bstride + (size_t)colB * ldb;
  const us* pBl = (MODE == 3) ? nullptr : Blo + (size_t)bz * bstride + (size_t)colB * ldb;

  f32x4 zero = {0.f, 0.f, 0.f, 0.f};
  f32x4 acc[4][4];
#pragma unroll
  for (int m = 0; m < 4; ++m)
#pragma unroll
    for (int n = 0; n < 4; ++n) acc[m][n] = zero;

  int lane = tid & 63, wvi = tid >> 6;
  int wr = wvi >> 1, wc = wvi & 1;
  int fr = lane & 15;
  int kob = (lane >> 4) << 4;  // byte offset of this lane's 8-elem k-group within 32-elem step

  for (int k0 = 0; k0 < K; k0 += 64) {
    const us *sAh, *sAl;
    if constexpr (MODE == 3) {
      if (k0 < 1024) { sAh = pAh + k0; sAl = pAl + k0; }
      else           { sAh = pA2h + (k0 - 1024); sAl = pA2l + (k0 - 1024); }
    } else { sAh = pAh + k0; sAl = pAl + k0; }
    stage_plane(sAh, lda, tAh, tid);
    stage_plane(pBh + k0, ldb, tBh, tid);
    stage_plane(sAl, lda, tAl, tid);
    if constexpr (MODE != 3) stage_plane(pBl + k0, ldb, tBl, tid);
    __syncthreads();
#pragma unroll
    for (int kk = 0; kk < 2; ++kk) {
      int cb = (kk << 6) + kob;
      bf16x8 ah[4], al[4], bh[4], bl[4];
#pragma unroll
      for (int m = 0; m < 4; ++m) {
        int ra = (wr << 6) + (m << 4) + fr;
        ah[m] = frag_ld(tAh, ra, cb);
        al[m] = frag_ld(tAl, ra, cb);
      }
#pragma unroll
      for (int n = 0; n < 4; ++n) {
        int rb = (wc << 6) + (n << 4) + fr;
        bh[n] = frag_ld(tBh, rb, cb);
        if constexpr (MODE != 3) bl[n] = frag_ld(tBl, rb, cb);
      }
#pragma unroll
      for (int m = 0; m < 4; ++m)
#pragma unroll
        for (int n = 0; n < 4; ++n) {
          acc[m][n] = mfma16(ah[m], bh[n], acc[m][n]);
          if constexpr (MODE != 3) acc[m][n] = mfma16(ah[m], bl[n], acc[m][n]);
          acc[m][n] = mfma16(al[m], bh[n], acc[m][n]);
        }
    }
    __syncthreads();
  }

#pragma unroll
  for (int m = 0; m < 4; ++m)
#pragma unroll
    for (int n = 0; n < 4; ++n)
#pragma unroll
      for (int j = 0; j < 4; ++j) {
        int r = rowA + (wr << 6) + (m << 4) + ((lane >> 4) << 2) + j;
        int c = colB + (wc << 6) + (n << 4) + (lane & 15);
        float v = acc[m][n][j];
        if constexpr (MODE == 0) {
          store_split((us*)out0, (us*)out1, (size_t)r * 1024 + c, v);
        } else if constexpr (MODE == 1) {
          ((float*)out0)[((size_t)r * NB + bz) * NS + c] = v;  // align[t][b][s]
        } else if constexpr (MODE == 2) {
          store_split((us*)out0, (us*)out1, ((size_t)bz * NT + r) * 1024 + c, v);
        } else {
          int bb = r >> 9, tt = r & 511;
          ((float*)out0)[((size_t)tt * NB + bb) * ND + c] = tanhf(v);  // attn[t][b][d]
        }
      }
}

// ---------------- launch ----------------
extern "C" void kernel_launch(void* const* d_in, const int* in_sizes, int n_in,
                              void* d_out, int out_size, void* d_ws, size_t ws_size,
                              hipStream_t stream) {
  (void)in_sizes; (void)n_in; (void)out_size; (void)ws_size;
  const float* inp = (const float*)d_in[0];   // [32][512][1024]
  const float* ctx = (const float*)d_in[1];   // [32][1024][1024]
  const float* Win = (const float*)d_in[2];   // [1024][1024] (e,d)
  const float* Wout = (const float*)d_in[3];  // [1024][2048] (d,f)
  float* out = (float*)d_out;

  char* w = (char*)d_ws;
  us* ctx_hi  = (us*)(w + 0);
  us* c_hi    = (us*)(w + 0);
  us* c_lo    = (us*)(w + 33554432);
  us* ctx_lo  = (us*)(w + 67108864);
  us* p_hi    = (us*)(w + 67108864);
  us* p_lo    = (us*)(w + 100663296);
  us* in_hi   = (us*)(w + 134217728);
  us* in_lo   = (us*)(w + 167772160);
  us* h_hi    = (us*)(w + 201326592);
  us* h_lo    = (us*)(w + 234881024);
  us* ctxT_lo = (us*)(w + 201326592);  // reuses h region after GEMM2
  us* win_hi  = (us*)(w + 268435456);
  us* win_lo  = (us*)(w + 270532608);
  us* wout_b  = (us*)(w + 272629760);

  us* ctxT_hi = (us*)d_out;            // attn region as scratch until GEMM4
  float* alignOut = out + 16777216;    // second half of d_out

  ga_split<<<2048, 256, 0, stream>>>(inp, in_hi, in_lo, 16777216L);
  ga_split<<<2048, 256, 0, stream>>>(ctx, ctx_hi, ctx_lo, 33554432L);
  ga_split<<<512, 256, 0, stream>>>(Win, win_hi, win_lo, 1048576L);
  ga_cvt<<<512, 256, 0, stream>>>(Wout, wout_b, 2097152L);

  // GEMM1: h = in @ W_in^T   (M=16384, N=1024, K=1024)
  ga_gemm<0><<<dim3(128, 8, 1), 256, 0, stream>>>(in_hi, in_lo, nullptr, nullptr,
                                                  win_hi, win_lo, h_hi, h_lo,
                                                  1024, 1024, 1024, 0L, 0L);
  // GEMM2: align = h @ ctx^T (batched over 32; M=512, N=1024, K=1024)
  ga_gemm<1><<<dim3(4, 8, 32), 256, 0, stream>>>(h_hi, h_lo, nullptr, nullptr,
                                                 ctx_hi, ctx_lo, alignOut, nullptr,
                                                 1024, 1024, 1024, 524288L, 1048576L);
  // ctx transpose+split (overwrites h region -> must follow GEMM2; stream-ordered)
  ga_transpose_split<<<dim3(16, 16, 32), 256, 0, stream>>>(ctx, ctxT_hi, ctxT_lo);
  // softmax in-place + P split planes
  ga_softmax<<<16384, 256, 0, stream>>>(alignOut, p_hi, p_lo);
  // GEMM3: c = P @ ctx (via ctxT planes; batched; M=512, N=1024, K=1024)
  ga_gemm<2><<<dim3(4, 8, 32), 256, 0, stream>>>(p_hi, p_lo, nullptr, nullptr,
                                                 ctxT_hi, ctxT_lo, c_hi, c_lo,
                                                 1024, 1024, 1024, 524288L, 1048576L);
  // GEMM4: attn = tanh(concat[c,in] @ W_out^T) (M=16384, N=1024, K=2048, 2-term)
  ga_gemm<3><<<dim3(128, 8, 1), 256, 0, stream>>>(c_hi, c_lo, in_hi, in_lo,
                                                  wout_b, nullptr, out, nullptr,
                                                  2048, 1024, 2048, 0L, 0L);
}